// Round 17
// baseline (73.212 us; speedup 1.0000x reference)
//
#include <hip/hip_runtime.h>
#include <stdint.h>

// Problem constants
#define NS 128   // n_seq (contraction dim, mean divisor)
#define NR 256   // S residues
#define CM 256   // c_m
#define CH 32    // c_hidden
#define CZ 128   // c_z

typedef __attribute__((ext_vector_type(4))) float f32x4;
typedef __attribute__((ext_vector_type(16))) float f32x16;
typedef __attribute__((ext_vector_type(8))) short bf16x8;   // 8 bf16 in 4 VGPRs
typedef __attribute__((ext_vector_type(4))) unsigned short u16x4;
typedef __attribute__((ext_vector_type(4))) unsigned int u32x4;

// Address-space typedefs for global_load_lds
typedef __attribute__((address_space(1))) const void GVT;
typedef __attribute__((address_space(3))) void LVT;

__device__ __forceinline__ unsigned short bf16rne(float x) {
    unsigned int u = __builtin_bit_cast(unsigned int, x);
    return (unsigned short)((u + 0x7FFFu + ((u >> 16) & 1u)) >> 16);
}

// Pack two f32 into one u32 of 2 bf16 — pure C++ (verified R12).
__device__ __forceinline__ unsigned int pack2_bf16(float lo, float hi) {
    return (unsigned int)bf16rne(lo) | ((unsigned int)bf16rne(hi) << 16);
}

// ---------------------------------------------------------------------------
// k0: repack Wa|Wb (16x16 B-frag layout, for k_lnproj) and Wo (32x32 B-frag).
// ---------------------------------------------------------------------------
__global__ __launch_bounds__(256) void k_wrepack(const float* __restrict__ Wa,
                                                 const float* __restrict__ Wb,
                                                 const float* __restrict__ Wo,
                                                 unsigned short* __restrict__ Wab_f,
                                                 unsigned short* __restrict__ Wo_f) {
    int idx = blockIdx.x * 256 + threadIdx.x;
    int l = idx & 63;
    int lo = l & 15, hi = l >> 4;
    int il = l & 31, h = l >> 5;
    if (idx < 2048) {
        int ks = (idx >> 6) & 7;
        int n = idx >> 9;
        int k = n * 16 + lo;
        bf16x8 v;
#pragma unroll
        for (int e = 0; e < 8; ++e) {
            int c = ks * 32 + hi * 8 + e;
            float wv = (k < CH) ? Wa[c * CH + k] : Wb[c * CH + (k - CH)];
            v[e] = (short)bf16rne(wv);
        }
        *reinterpret_cast<bf16x8*>(Wab_f + (size_t)idx * 8) = v;
    } else if (idx < 2048 + 16384) {
        int t = idx - 2048;
        int ks2 = (t >> 6) & 1, kt = (t >> 7) & 3, c = t >> 9;
        bf16x8 v;
#pragma unroll
        for (int e = 0; e < 8; ++e) {
            int d = ks2 * 16 + h * 8 + e;
            v[e] = (short)bf16rne(Wo[(size_t)(c * 32 + d) * CZ + kt * 32 + il]);
        }
        *reinterpret_cast<bf16x8*>(Wo_f + (size_t)t * 8) = v;
    }
}

// ---------------------------------------------------------------------------
// k1: LayerNorm + dual projection via MFMA (verified; unchanged).
// ---------------------------------------------------------------------------
__global__ __launch_bounds__(256) void k_lnproj(const float* __restrict__ m,
                                                const float* __restrict__ lnw,
                                                const float* __restrict__ lnb,
                                                const float* __restrict__ ba,
                                                const float* __restrict__ bb,
                                                const unsigned short* __restrict__ Wab_f,
                                                unsigned short* __restrict__ a_n,
                                                unsigned short* __restrict__ b_n) {
    __shared__ unsigned short mn_lds[64 * 256];   // 32 KB, rows of 512 B, XOR-swizzled
    const int tid = threadIdx.x, l = tid & 63, w = tid >> 6;
    const int lo = l & 15, hi = l >> 4;
    const int R0 = blockIdx.x * 64;

    float4 wv = *reinterpret_cast<const float4*>(lnw + l * 4);
    float4 bv = *reinterpret_cast<const float4*>(lnb + l * 4);

    for (int t = 0; t < 16; ++t) {
        int row = w * 16 + t;
        int gr = R0 + row;
        float4 x = *reinterpret_cast<const float4*>(m + (size_t)gr * CM + l * 4);
        float sum = x.x + x.y + x.z + x.w;
        float sq = x.x * x.x + x.y * x.y + x.z * x.z + x.w * x.w;
#pragma unroll
        for (int off = 32; off; off >>= 1) {
            sum += __shfl_xor(sum, off);
            sq  += __shfl_xor(sq, off);
        }
        float mu = sum * (1.f / CM);
        float rstd = rsqrtf(sq * (1.f / CM) - mu * mu + 1e-5f);
        u16x4 pk;
        pk[0] = bf16rne((x.x - mu) * rstd * wv.x + bv.x);
        pk[1] = bf16rne((x.y - mu) * rstd * wv.y + bv.y);
        pk[2] = bf16rne((x.z - mu) * rstd * wv.z + bv.z);
        pk[3] = bf16rne((x.w - mu) * rstd * wv.w + bv.w);
        int byte = row * 512 + l * 8;
        byte ^= (row & 7) << 4;
        *reinterpret_cast<u16x4*>(reinterpret_cast<char*>(mn_lds) + byte) = pk;
    }

    f32x4 acc[4];
#pragma unroll
    for (int n = 0; n < 4; ++n) acc[n] = (f32x4){0.f, 0.f, 0.f, 0.f};
    const int arow = w * 16 + lo;
#pragma unroll
    for (int ks = 0; ks < 8; ++ks) {
        int byte = arow * 512 + ks * 64 + hi * 16;
        byte ^= (arow & 7) << 4;
        bf16x8 afrag = *reinterpret_cast<const bf16x8*>(reinterpret_cast<const char*>(mn_lds) + byte);
#pragma unroll
        for (int n = 0; n < 4; ++n) {
            bf16x8 bfrag = *reinterpret_cast<const bf16x8*>(Wab_f + (size_t)((n * 8 + ks) * 64 + l) * 8);
            acc[n] = __builtin_amdgcn_mfma_f32_16x16x32_bf16(afrag, bfrag, acc[n], 0, 0, 0);
        }
    }
#pragma unroll
    for (int n = 0; n < 4; ++n) {
        int k = n * 16 + lo;
        float bias = (k < CH) ? ba[k] : bb[k - CH];
#pragma unroll
        for (int r = 0; r < 4; ++r) {
            int gr = R0 + w * 16 + hi * 4 + r;
            unsigned short hv = bf16rne(acc[n][r] + bias);
            if (k < CH) a_n[(size_t)gr * CH + k] = hv;
            else        b_n[(size_t)gr * CH + (k - CH)] = hv;
        }
    }
}

// ---------------------------------------------------------------------------
// k2: repack a_n/b_n into 32x32-MFMA fragment-major layouts (verified; unchanged).
// ---------------------------------------------------------------------------
__global__ __launch_bounds__(256) void k_abrepack(const unsigned short* __restrict__ a_n,
                                                  const unsigned short* __restrict__ b_n,
                                                  unsigned short* __restrict__ a_f,
                                                  unsigned short* __restrict__ b_f) {
    int idx = blockIdx.x * 256 + threadIdx.x;
    int l = idx & 63, il = l & 31, h = (l >> 5) & 1;
    if (idx < 131072) {
        int ks = (idx >> 6) & 7, ib = (idx >> 9) & 7, c = idx >> 12;
        int i = ib * 32 + il;
        bf16x8 v;
#pragma unroll
        for (int e = 0; e < 8; ++e) {
            int s = ks * 16 + h * 8 + e;
            v[e] = (short)a_n[((size_t)s * NR + i) * CH + c];
        }
        *reinterpret_cast<bf16x8*>(a_f + (size_t)idx * 8) = v;
    } else {
        int t = idx - 131072;
        int ks = (t >> 6) & 7, jl = (t >> 9) & 7, jb = t >> 12;
        int j = jb * 8 + jl;
        bf16x8 v;
#pragma unroll
        for (int e = 0; e < 8; ++e) {
            int s = ks * 16 + h * 8 + e;
            v[e] = (short)b_n[((size_t)s * NR + j) * CH + il];
        }
        *reinterpret_cast<bf16x8*>(b_f + (size_t)t * 8) = v;
    }
}

// ---------------------------------------------------------------------------
// k3: fused outer-product-mean + Wo projection (32x32 MFMA datapath verified
// R12; LDS operand staging verified R14). This round:
//  (1) __launch_bounds__(512, 2): request the TRUE occupancy (1 block/CU at
//      96 KB LDS) -> VGPR cap 256 (R14's implicit 88 strangled pipelining;
//      R13's cap 64 spilled zacc).
//  (2) global_load_lds (16 B/lane, linear dest) for ALL staging: no VMEM->
//      VGPR->LDS roundtrip; c+1 loads issued before compute drain at the
//      compiler's vmcnt(0) before the barrier (latency hidden under MFMA).
// ---------------------------------------------------------------------------
__global__ __launch_bounds__(512, 2) void k_outer(const unsigned short* __restrict__ a_f,
                                                  const unsigned short* __restrict__ b_f,
                                                  const unsigned short* __restrict__ Wo_f,
                                                  const float* __restrict__ bo,
                                                  float* __restrict__ out) {
    __shared__ unsigned short b_lds[32768];    // 64 KB: [jl][ks][lane][e]
    __shared__ unsigned short s_af[2][4096];   // 2 x 8 KB: af slice for c
    __shared__ unsigned short s_wo[2][4096];   // 2 x 8 KB: wof slice for c
    const int tid = threadIdx.x, l = tid & 63, w = tid >> 6;   // w in 0..7
    const int il = l & 31, h = l >> 5;
    const int bi = blockIdx.x >> 5, bj = blockIdx.x & 31;

    // Stage the block's b slice (64 KB) + c=0 operand slices, all direct-to-LDS.
    {
        const unsigned short* srcB = b_f + (size_t)bj * 32768;
#pragma unroll
        for (int it = 0; it < 8; ++it) {
            __builtin_amdgcn_global_load_lds((GVT*)(srcB + it * 4096 + tid * 8),
                                             (LVT*)(b_lds + it * 4096 + tid * 8), 16, 0, 0);
        }
        __builtin_amdgcn_global_load_lds((GVT*)(a_f + (size_t)bi * 4096 + tid * 8),
                                         (LVT*)(&s_af[0][tid * 8]), 16, 0, 0);
        __builtin_amdgcn_global_load_lds((GVT*)(Wo_f + tid * 8),
                                         (LVT*)(&s_wo[0][tid * 8]), 16, 0, 0);
    }
    __syncthreads();

    // Wave's c-invariant b fragments: A[row=d=l&31][k=s]  (kept live: cap=256)
    bf16x8 bfr[8];
#pragma unroll
    for (int ks = 0; ks < 8; ++ks)
        bfr[ks] = *reinterpret_cast<const bf16x8*>(b_lds + ((w * 8 + ks) * 64 + l) * 8);

    f32x16 zacc[4];
#pragma unroll
    for (int kt = 0; kt < 4; ++kt)
        zacc[kt] = (f32x16){0.f,0.f,0.f,0.f,0.f,0.f,0.f,0.f,0.f,0.f,0.f,0.f,0.f,0.f,0.f,0.f};

    for (int c = 0; c < 32; ++c) {
        const int cur = c & 1, nxt = cur ^ 1;

        // Issue next-c staging direct to LDS (drains at the barrier's vmcnt(0))
        if (c + 1 < 32) {
            __builtin_amdgcn_global_load_lds(
                (GVT*)(a_f + (size_t)((c + 1) * 8 + bi) * 4096 + tid * 8),
                (LVT*)(&s_af[nxt][tid * 8]), 16, 0, 0);
            __builtin_amdgcn_global_load_lds(
                (GVT*)(Wo_f + (size_t)(c + 1) * 4096 + tid * 8),
                (LVT*)(&s_wo[nxt][tid * 8]), 16, 0, 0);
        }

        // Operands for this c from LDS (conflict-free: lane-consecutive 16B)
        bf16x8 af[8];
#pragma unroll
        for (int ks = 0; ks < 8; ++ks)
            af[ks] = *reinterpret_cast<const bf16x8*>(&s_af[cur][(ks * 64 + l) * 8]);
        bf16x8 wof0[4], wof1[4];
#pragma unroll
        for (int kt = 0; kt < 4; ++kt) {
            wof0[kt] = *reinterpret_cast<const bf16x8*>(&s_wo[cur][((kt * 2 + 0) * 64 + l) * 8]);
            wof1[kt] = *reinterpret_cast<const bf16x8*>(&s_wo[cur][((kt * 2 + 1) * 64 + l) * 8]);
        }

        // Stage A: O^T[d][i], K=128 over s — two independent 4-chains
        f32x16 o0 = (f32x16){0.f,0.f,0.f,0.f,0.f,0.f,0.f,0.f,0.f,0.f,0.f,0.f,0.f,0.f,0.f,0.f};
        f32x16 o1 = (f32x16){0.f,0.f,0.f,0.f,0.f,0.f,0.f,0.f,0.f,0.f,0.f,0.f,0.f,0.f,0.f,0.f};
#pragma unroll
        for (int ks = 0; ks < 4; ++ks) {
            o0 = __builtin_amdgcn_mfma_f32_32x32x16_bf16(bfr[ks],     af[ks],     o0, 0, 0, 0);
            o1 = __builtin_amdgcn_mfma_f32_32x32x16_bf16(bfr[ks + 4], af[ks + 4], o1, 0, 0, 0);
        }
        f32x16 o = o0 + o1;

        // Transpose to PA[row=i][k=d] (verified R12)
        unsigned int u0 = pack2_bf16(o[0],  o[1]);
        unsigned int u1 = pack2_bf16(o[2],  o[3]);
        unsigned int u2 = pack2_bf16(o[4],  o[5]);
        unsigned int u3 = pack2_bf16(o[6],  o[7]);
        unsigned int u4 = pack2_bf16(o[8],  o[9]);
        unsigned int u5 = pack2_bf16(o[10], o[11]);
        unsigned int u6 = pack2_bf16(o[12], o[13]);
        unsigned int u7 = pack2_bf16(o[14], o[15]);
        unsigned int p0 = __shfl_xor(u0, 32);
        unsigned int p1 = __shfl_xor(u1, 32);
        unsigned int p2 = __shfl_xor(u2, 32);
        unsigned int p3 = __shfl_xor(u3, 32);
        unsigned int p4 = __shfl_xor(u4, 32);
        unsigned int p5 = __shfl_xor(u5, 32);
        unsigned int p6 = __shfl_xor(u6, 32);
        unsigned int p7 = __shfl_xor(u7, 32);
        u32x4 t0 = h ? (u32x4){p0, p1, u0, u1} : (u32x4){u0, u1, p0, p1};   // d0..7
        u32x4 t1 = h ? (u32x4){p2, p3, u2, u3} : (u32x4){u2, u3, p2, p3};   // d8..15
        u32x4 t2 = h ? (u32x4){p4, p5, u4, u5} : (u32x4){u4, u5, p4, p5};   // d16..23
        u32x4 t3 = h ? (u32x4){p6, p7, u6, u7} : (u32x4){u6, u7, p6, p7};   // d24..31
        u32x4 lo16 = h ? t1 : t0;   // A-operand k = h*8+e over d0..15
        u32x4 hi16 = h ? t3 : t2;   // A-operand k = h*8+e over d16..31
        bf16x8 paA = __builtin_bit_cast(bf16x8, lo16);
        bf16x8 paB = __builtin_bit_cast(bf16x8, hi16);

        // Stage B: z[i, kt*32+il] += PA @ Wo_c
#pragma unroll
        for (int kt = 0; kt < 4; ++kt) {
            zacc[kt] = __builtin_amdgcn_mfma_f32_32x32x16_bf16(paA, wof0[kt], zacc[kt], 0, 0, 0);
            zacc[kt] = __builtin_amdgcn_mfma_f32_32x32x16_bf16(paB, wof1[kt], zacc[kt], 0, 0, 0);
        }

        __syncthreads();   // drains the c+1 global_load_lds (vmcnt) + orders reads
    }

    // Epilogue: /n_seq + bo.  D layout: col=il, row=(r&3)+8*(r>>2)+4h (verified R12)
    const int j = bj * 8 + w;
#pragma unroll
    for (int kt = 0; kt < 4; ++kt) {
        float bok = bo[kt * 32 + il];
#pragma unroll
        for (int r = 0; r < 16; ++r) {
            int i = bi * 32 + (r & 3) + 8 * (r >> 2) + 4 * h;
            out[((size_t)i * NR + j) * CZ + kt * 32 + il] = zacc[kt][r] * (1.f / NS) + bok;
        }
    }
}

// ---------------------------------------------------------------------------
extern "C" void kernel_launch(void* const* d_in, const int* in_sizes, int n_in,
                              void* d_out, int out_size, void* d_ws, size_t ws_size,
                              hipStream_t stream) {
    const float* m   = (const float*)d_in[0];
    const float* lnw = (const float*)d_in[1];
    const float* lnb = (const float*)d_in[2];
    const float* Wa  = (const float*)d_in[3];
    const float* ba  = (const float*)d_in[4];
    const float* Wb  = (const float*)d_in[5];
    const float* bb  = (const float*)d_in[6];
    const float* Wo  = (const float*)d_in[7];
    const float* bo  = (const float*)d_in[8];
    float* out = (float*)d_out;

    // ws layout (ushort units): a_n | b_n | a_f | b_f | Wab_f | Wo_f
    unsigned short* ws    = (unsigned short*)d_ws;
    unsigned short* a_n   = ws;
    unsigned short* b_n   = ws + 1048576;
    unsigned short* a_f   = ws + 2097152;
    unsigned short* b_f   = ws + 3145728;
    unsigned short* Wab_f = ws + 4194304;
    unsigned short* Wo_f  = ws + 4210688;
    const size_t WS_NEEDED = (size_t)(4210688 + 131072) * 2;
    if (ws_size < WS_NEEDED) return;   // diagnosable: output stays poisoned

    k_wrepack<<<72, 256, 0, stream>>>(Wa, Wb, Wo, Wab_f, Wo_f);
    k_lnproj<<<512, 256, 0, stream>>>(m, lnw, lnb, ba, bb, Wab_f, a_n, b_n);
    k_abrepack<<<1024, 256, 0, stream>>>(a_n, b_n, a_f, b_f);
    k_outer<<<256, 512, 0, stream>>>(a_f, b_f, Wo_f, bo, out);
}

// Round 18
// 67.676 us; speedup vs baseline: 1.0818x; 1.0818x over previous
//
#include <hip/hip_runtime.h>
#include <stdint.h>

// Problem constants
#define NS 128   // n_seq (contraction dim, mean divisor)
#define NR 256   // S residues
#define CM 256   // c_m
#define CH 32    // c_hidden
#define CZ 128   // c_z

typedef __attribute__((ext_vector_type(4))) float f32x4;
typedef __attribute__((ext_vector_type(16))) float f32x16;
typedef __attribute__((ext_vector_type(8))) short bf16x8;   // 8 bf16 in 4 VGPRs
typedef __attribute__((ext_vector_type(4))) unsigned short u16x4;
typedef __attribute__((ext_vector_type(4))) unsigned int u32x4;

__device__ __forceinline__ unsigned short bf16rne(float x) {
    unsigned int u = __builtin_bit_cast(unsigned int, x);
    return (unsigned short)((u + 0x7FFFu + ((u >> 16) & 1u)) >> 16);
}

// Pack two f32 into one u32 of 2 bf16 — pure C++ (verified R12).
__device__ __forceinline__ unsigned int pack2_bf16(float lo, float hi) {
    return (unsigned int)bf16rne(lo) | ((unsigned int)bf16rne(hi) << 16);
}

// ---------------------------------------------------------------------------
// k0: repack Wa|Wb (16x16 B-frag layout, for k_lnproj) and Wo (32x32 B-frag).
// ---------------------------------------------------------------------------
__global__ __launch_bounds__(256) void k_wrepack(const float* __restrict__ Wa,
                                                 const float* __restrict__ Wb,
                                                 const float* __restrict__ Wo,
                                                 unsigned short* __restrict__ Wab_f,
                                                 unsigned short* __restrict__ Wo_f) {
    int idx = blockIdx.x * 256 + threadIdx.x;
    int l = idx & 63;
    int lo = l & 15, hi = l >> 4;
    int il = l & 31, h = l >> 5;
    if (idx < 2048) {
        int ks = (idx >> 6) & 7;
        int n = idx >> 9;
        int k = n * 16 + lo;
        bf16x8 v;
#pragma unroll
        for (int e = 0; e < 8; ++e) {
            int c = ks * 32 + hi * 8 + e;
            float wv = (k < CH) ? Wa[c * CH + k] : Wb[c * CH + (k - CH)];
            v[e] = (short)bf16rne(wv);
        }
        *reinterpret_cast<bf16x8*>(Wab_f + (size_t)idx * 8) = v;
    } else if (idx < 2048 + 16384) {
        int t = idx - 2048;
        int ks2 = (t >> 6) & 1, kt = (t >> 7) & 3, c = t >> 9;
        bf16x8 v;
#pragma unroll
        for (int e = 0; e < 8; ++e) {
            int d = ks2 * 16 + h * 8 + e;
            v[e] = (short)bf16rne(Wo[(size_t)(c * 32 + d) * CZ + kt * 32 + il]);
        }
        *reinterpret_cast<bf16x8*>(Wo_f + (size_t)t * 8) = v;
    }
}

// ---------------------------------------------------------------------------
// k1: LayerNorm + dual projection via MFMA (verified; unchanged).
// ---------------------------------------------------------------------------
__global__ __launch_bounds__(256) void k_lnproj(const float* __restrict__ m,
                                                const float* __restrict__ lnw,
                                                const float* __restrict__ lnb,
                                                const float* __restrict__ ba,
                                                const float* __restrict__ bb,
                                                const unsigned short* __restrict__ Wab_f,
                                                unsigned short* __restrict__ a_n,
                                                unsigned short* __restrict__ b_n) {
    __shared__ unsigned short mn_lds[64 * 256];   // 32 KB, rows of 512 B, XOR-swizzled
    const int tid = threadIdx.x, l = tid & 63, w = tid >> 6;
    const int lo = l & 15, hi = l >> 4;
    const int R0 = blockIdx.x * 64;

    float4 wv = *reinterpret_cast<const float4*>(lnw + l * 4);
    float4 bv = *reinterpret_cast<const float4*>(lnb + l * 4);

    for (int t = 0; t < 16; ++t) {
        int row = w * 16 + t;
        int gr = R0 + row;
        float4 x = *reinterpret_cast<const float4*>(m + (size_t)gr * CM + l * 4);
        float sum = x.x + x.y + x.z + x.w;
        float sq = x.x * x.x + x.y * x.y + x.z * x.z + x.w * x.w;
#pragma unroll
        for (int off = 32; off; off >>= 1) {
            sum += __shfl_xor(sum, off);
            sq  += __shfl_xor(sq, off);
        }
        float mu = sum * (1.f / CM);
        float rstd = rsqrtf(sq * (1.f / CM) - mu * mu + 1e-5f);
        u16x4 pk;
        pk[0] = bf16rne((x.x - mu) * rstd * wv.x + bv.x);
        pk[1] = bf16rne((x.y - mu) * rstd * wv.y + bv.y);
        pk[2] = bf16rne((x.z - mu) * rstd * wv.z + bv.z);
        pk[3] = bf16rne((x.w - mu) * rstd * wv.w + bv.w);
        int byte = row * 512 + l * 8;
        byte ^= (row & 7) << 4;
        *reinterpret_cast<u16x4*>(reinterpret_cast<char*>(mn_lds) + byte) = pk;
    }

    f32x4 acc[4];
#pragma unroll
    for (int n = 0; n < 4; ++n) acc[n] = (f32x4){0.f, 0.f, 0.f, 0.f};
    const int arow = w * 16 + lo;
#pragma unroll
    for (int ks = 0; ks < 8; ++ks) {
        int byte = arow * 512 + ks * 64 + hi * 16;
        byte ^= (arow & 7) << 4;
        bf16x8 afrag = *reinterpret_cast<const bf16x8*>(reinterpret_cast<const char*>(mn_lds) + byte);
#pragma unroll
        for (int n = 0; n < 4; ++n) {
            bf16x8 bfrag = *reinterpret_cast<const bf16x8*>(Wab_f + (size_t)((n * 8 + ks) * 64 + l) * 8);
            acc[n] = __builtin_amdgcn_mfma_f32_16x16x32_bf16(afrag, bfrag, acc[n], 0, 0, 0);
        }
    }
#pragma unroll
    for (int n = 0; n < 4; ++n) {
        int k = n * 16 + lo;
        float bias = (k < CH) ? ba[k] : bb[k - CH];
#pragma unroll
        for (int r = 0; r < 4; ++r) {
            int gr = R0 + w * 16 + hi * 4 + r;
            unsigned short hv = bf16rne(acc[n][r] + bias);
            if (k < CH) a_n[(size_t)gr * CH + k] = hv;
            else        b_n[(size_t)gr * CH + (k - CH)] = hv;
        }
    }
}

// ---------------------------------------------------------------------------
// k2: repack a_n/b_n into 32x32-MFMA fragment-major layouts (verified; unchanged).
// ---------------------------------------------------------------------------
__global__ __launch_bounds__(256) void k_abrepack(const unsigned short* __restrict__ a_n,
                                                  const unsigned short* __restrict__ b_n,
                                                  unsigned short* __restrict__ a_f,
                                                  unsigned short* __restrict__ b_f) {
    int idx = blockIdx.x * 256 + threadIdx.x;
    int l = idx & 63, il = l & 31, h = (l >> 5) & 1;
    if (idx < 131072) {
        int ks = (idx >> 6) & 7, ib = (idx >> 9) & 7, c = idx >> 12;
        int i = ib * 32 + il;
        bf16x8 v;
#pragma unroll
        for (int e = 0; e < 8; ++e) {
            int s = ks * 16 + h * 8 + e;
            v[e] = (short)a_n[((size_t)s * NR + i) * CH + c];
        }
        *reinterpret_cast<bf16x8*>(a_f + (size_t)idx * 8) = v;
    } else {
        int t = idx - 131072;
        int ks = (t >> 6) & 7, jl = (t >> 9) & 7, jb = t >> 12;
        int j = jb * 8 + jl;
        bf16x8 v;
#pragma unroll
        for (int e = 0; e < 8; ++e) {
            int s = ks * 16 + h * 8 + e;
            v[e] = (short)b_n[((size_t)s * NR + j) * CH + il];
        }
        *reinterpret_cast<bf16x8*>(b_f + (size_t)t * 8) = v;
    }
}

// ---------------------------------------------------------------------------
// k3: fused outer-product-mean + Wo projection (32x32 MFMA datapath verified
// R12; reg-staged LDS double-buffer verified R14 at 52 us).
// NEW: cross-c software pipeline — iteration c runs stage B for c-1 (using
// carried pa/wofP) CONCURRENT with stage A for c. The carried registers'
// LDS slot is overwritten by c+1's staging, so the compiler CANNOT re-read
// them: register residency is forced by correctness (R6/R15/R17 showed the
// allocator never holds operands voluntarily).
// Order per c: globals(c+1) -> ds_read af(c) -> MFMA-B(c-1) -> MFMA-A(c)
//              -> ds_read wofP(c) -> transpose(c) -> ds_write(c+1) -> barrier.
// ---------------------------------------------------------------------------
__global__ __launch_bounds__(512, 2) void k_outer(const unsigned short* __restrict__ a_f,
                                                  const unsigned short* __restrict__ b_f,
                                                  const unsigned short* __restrict__ Wo_f,
                                                  const float* __restrict__ bo,
                                                  float* __restrict__ out) {
    __shared__ unsigned short b_lds[32768];    // 64 KB: [jl][ks][lane][e]
    __shared__ unsigned short s_af[2][4096];   // 2 x 8 KB: af slice per c
    __shared__ unsigned short s_wo[2][4096];   // 2 x 8 KB: wof slice per c
    const int tid = threadIdx.x, l = tid & 63, w = tid >> 6;   // w in 0..7
    const int il = l & 31, h = l >> 5;
    const int bi = blockIdx.x >> 5, bj = blockIdx.x & 31;

    // Stage b slice (reg roundtrip) + c=0 operands; prefetch c=1 to regs.
    {
        const unsigned short* src = b_f + (size_t)bj * 32768;
#pragma unroll
        for (int it = 0; it < 8; ++it) {
            int off = it * 4096 + tid * 8;
            *reinterpret_cast<bf16x8*>(b_lds + off) =
                *reinterpret_cast<const bf16x8*>(src + off);
        }
        bf16x8 rA0 = *reinterpret_cast<const bf16x8*>(a_f + (size_t)bi * 4096 + tid * 8);
        bf16x8 rW0 = *reinterpret_cast<const bf16x8*>(Wo_f + tid * 8);
        *reinterpret_cast<bf16x8*>(&s_af[0][tid * 8]) = rA0;
        *reinterpret_cast<bf16x8*>(&s_wo[0][tid * 8]) = rW0;
    }
    bf16x8 rA1 = *reinterpret_cast<const bf16x8*>(a_f + (size_t)(8 + bi) * 4096 + tid * 8);
    bf16x8 rW1 = *reinterpret_cast<const bf16x8*>(Wo_f + (size_t)4096 + tid * 8);
    __syncthreads();   // b_lds + buf0 ready

    // Wave's c-invariant b fragments: A[row=d=l&31][k=s]
    bf16x8 bfr[8];
#pragma unroll
    for (int ks = 0; ks < 8; ++ks)
        bfr[ks] = *reinterpret_cast<const bf16x8*>(b_lds + ((w * 8 + ks) * 64 + l) * 8);

    f32x16 zacc[4];
#pragma unroll
    for (int kt = 0; kt < 4; ++kt)
        zacc[kt] = (f32x16){0.f,0.f,0.f,0.f,0.f,0.f,0.f,0.f,0.f,0.f,0.f,0.f,0.f,0.f,0.f,0.f};

    // ---- Prologue: stage A for c=0 -> carried pa/wofP; stage buf1 for c=1.
    bf16x8 paA, paB;      // carried transposed O (c-1)
    bf16x8 wofP[8];       // carried Wo fragments (c-1): [0..3]=ks2 0, [4..7]=ks2 1
    {
        bf16x8 af[8];
#pragma unroll
        for (int ks = 0; ks < 8; ++ks)
            af[ks] = *reinterpret_cast<const bf16x8*>(&s_af[0][(ks * 64 + l) * 8]);
#pragma unroll
        for (int kt = 0; kt < 4; ++kt) {
            wofP[kt]     = *reinterpret_cast<const bf16x8*>(&s_wo[0][((kt * 2 + 0) * 64 + l) * 8]);
            wofP[kt + 4] = *reinterpret_cast<const bf16x8*>(&s_wo[0][((kt * 2 + 1) * 64 + l) * 8]);
        }
        f32x16 o0 = (f32x16){0.f,0.f,0.f,0.f,0.f,0.f,0.f,0.f,0.f,0.f,0.f,0.f,0.f,0.f,0.f,0.f};
        f32x16 o1 = o0;
#pragma unroll
        for (int ks = 0; ks < 4; ++ks) {
            o0 = __builtin_amdgcn_mfma_f32_32x32x16_bf16(bfr[ks],     af[ks],     o0, 0, 0, 0);
            o1 = __builtin_amdgcn_mfma_f32_32x32x16_bf16(bfr[ks + 4], af[ks + 4], o1, 0, 0, 0);
        }
        f32x16 o = o0 + o1;
        unsigned int u0 = pack2_bf16(o[0],  o[1]),  u1 = pack2_bf16(o[2],  o[3]);
        unsigned int u2 = pack2_bf16(o[4],  o[5]),  u3 = pack2_bf16(o[6],  o[7]);
        unsigned int u4 = pack2_bf16(o[8],  o[9]),  u5 = pack2_bf16(o[10], o[11]);
        unsigned int u6 = pack2_bf16(o[12], o[13]), u7 = pack2_bf16(o[14], o[15]);
        unsigned int p0 = __shfl_xor(u0, 32), p1 = __shfl_xor(u1, 32);
        unsigned int p2 = __shfl_xor(u2, 32), p3 = __shfl_xor(u3, 32);
        unsigned int p4 = __shfl_xor(u4, 32), p5 = __shfl_xor(u5, 32);
        unsigned int p6 = __shfl_xor(u6, 32), p7 = __shfl_xor(u7, 32);
        u32x4 t0 = h ? (u32x4){p0, p1, u0, u1} : (u32x4){u0, u1, p0, p1};
        u32x4 t1 = h ? (u32x4){p2, p3, u2, u3} : (u32x4){u2, u3, p2, p3};
        u32x4 t2 = h ? (u32x4){p4, p5, u4, u5} : (u32x4){u4, u5, p4, p5};
        u32x4 t3 = h ? (u32x4){p6, p7, u6, u7} : (u32x4){u6, u7, p6, p7};
        paA = __builtin_bit_cast(bf16x8, h ? t1 : t0);
        paB = __builtin_bit_cast(bf16x8, h ? t3 : t2);
        // stage c=1 into buf1
        *reinterpret_cast<bf16x8*>(&s_af[1][tid * 8]) = rA1;
        *reinterpret_cast<bf16x8*>(&s_wo[1][tid * 8]) = rW1;
    }
    __syncthreads();   // buf1 ready

    // ---- Main loop: iteration c does stage B(c-1) + stage A(c).
    for (int c = 1; c < 32; ++c) {
        const int cur = c & 1, nxt = cur ^ 1;

        // T14 early-issue: globals for c+1
        bf16x8 rA, rW;
        if (c < 31) {
            rA = *reinterpret_cast<const bf16x8*>(a_f + (size_t)((c + 1) * 8 + bi) * 4096 + tid * 8);
            rW = *reinterpret_cast<const bf16x8*>(Wo_f + (size_t)(c + 1) * 4096 + tid * 8);
        }

        // ds_read af(c) early — latency hides under MFMA-B
        bf16x8 af[8];
#pragma unroll
        for (int ks = 0; ks < 8; ++ks)
            af[ks] = *reinterpret_cast<const bf16x8*>(&s_af[cur][(ks * 64 + l) * 8]);

        // Stage B (c-1): uses carried paA/paB/wofP — independent of af reads
#pragma unroll
        for (int kt = 0; kt < 4; ++kt) {
            zacc[kt] = __builtin_amdgcn_mfma_f32_32x32x16_bf16(paA, wofP[kt],     zacc[kt], 0, 0, 0);
            zacc[kt] = __builtin_amdgcn_mfma_f32_32x32x16_bf16(paB, wofP[kt + 4], zacc[kt], 0, 0, 0);
        }

        // Stage A (c)
        f32x16 o0 = (f32x16){0.f,0.f,0.f,0.f,0.f,0.f,0.f,0.f,0.f,0.f,0.f,0.f,0.f,0.f,0.f,0.f};
        f32x16 o1 = o0;
#pragma unroll
        for (int ks = 0; ks < 4; ++ks) {
            o0 = __builtin_amdgcn_mfma_f32_32x32x16_bf16(bfr[ks],     af[ks],     o0, 0, 0, 0);
            o1 = __builtin_amdgcn_mfma_f32_32x32x16_bf16(bfr[ks + 4], af[ks + 4], o1, 0, 0, 0);
        }
        f32x16 o = o0 + o1;

        // wofP(c) for next iteration's stage B (old wofP fully consumed above)
#pragma unroll
        for (int kt = 0; kt < 4; ++kt) {
            wofP[kt]     = *reinterpret_cast<const bf16x8*>(&s_wo[cur][((kt * 2 + 0) * 64 + l) * 8]);
            wofP[kt + 4] = *reinterpret_cast<const bf16x8*>(&s_wo[cur][((kt * 2 + 1) * 64 + l) * 8]);
        }

        // Transpose o(c) -> carried paA/paB (verified R12)
        unsigned int u0 = pack2_bf16(o[0],  o[1]),  u1 = pack2_bf16(o[2],  o[3]);
        unsigned int u2 = pack2_bf16(o[4],  o[5]),  u3 = pack2_bf16(o[6],  o[7]);
        unsigned int u4 = pack2_bf16(o[8],  o[9]),  u5 = pack2_bf16(o[10], o[11]);
        unsigned int u6 = pack2_bf16(o[12], o[13]), u7 = pack2_bf16(o[14], o[15]);
        unsigned int p0 = __shfl_xor(u0, 32), p1 = __shfl_xor(u1, 32);
        unsigned int p2 = __shfl_xor(u2, 32), p3 = __shfl_xor(u3, 32);
        unsigned int p4 = __shfl_xor(u4, 32), p5 = __shfl_xor(u5, 32);
        unsigned int p6 = __shfl_xor(u6, 32), p7 = __shfl_xor(u7, 32);
        u32x4 t0 = h ? (u32x4){p0, p1, u0, u1} : (u32x4){u0, u1, p0, p1};
        u32x4 t1 = h ? (u32x4){p2, p3, u2, u3} : (u32x4){u2, u3, p2, p3};
        u32x4 t2 = h ? (u32x4){p4, p5, u4, u5} : (u32x4){u4, u5, p4, p5};
        u32x4 t3 = h ? (u32x4){p6, p7, u6, u7} : (u32x4){u6, u7, p6, p7};
        paA = __builtin_bit_cast(bf16x8, h ? t1 : t0);
        paB = __builtin_bit_cast(bf16x8, h ? t3 : t2);

        // Stage c+1 into buf[nxt]; barrier flips buffers
        if (c < 31) {
            *reinterpret_cast<bf16x8*>(&s_af[nxt][tid * 8]) = rA;
            *reinterpret_cast<bf16x8*>(&s_wo[nxt][tid * 8]) = rW;
        }
        __syncthreads();
    }

    // ---- Epilogue: stage B for c=31
#pragma unroll
    for (int kt = 0; kt < 4; ++kt) {
        zacc[kt] = __builtin_amdgcn_mfma_f32_32x32x16_bf16(paA, wofP[kt],     zacc[kt], 0, 0, 0);
        zacc[kt] = __builtin_amdgcn_mfma_f32_32x32x16_bf16(paB, wofP[kt + 4], zacc[kt], 0, 0, 0);
    }

    // C-write: /n_seq + bo.  D layout: col=il, row=(r&3)+8*(r>>2)+4h (verified R12)
    const int j = bj * 8 + w;
#pragma unroll
    for (int kt = 0; kt < 4; ++kt) {
        float bok = bo[kt * 32 + il];
#pragma unroll
        for (int r = 0; r < 16; ++r) {
            int i = bi * 32 + (r & 3) + 8 * (r >> 2) + 4 * h;
            out[((size_t)i * NR + j) * CZ + kt * 32 + il] = zacc[kt][r] * (1.f / NS) + bok;
        }
    }
}

// ---------------------------------------------------------------------------
extern "C" void kernel_launch(void* const* d_in, const int* in_sizes, int n_in,
                              void* d_out, int out_size, void* d_ws, size_t ws_size,
                              hipStream_t stream) {
    const float* m   = (const float*)d_in[0];
    const float* lnw = (const float*)d_in[1];
    const float* lnb = (const float*)d_in[2];
    const float* Wa  = (const float*)d_in[3];
    const float* ba  = (const float*)d_in[4];
    const float* Wb  = (const float*)d_in[5];
    const float* bb  = (const float*)d_in[6];
    const float* Wo  = (const float*)d_in[7];
    const float* bo  = (const float*)d_in[8];
    float* out = (float*)d_out;

    // ws layout (ushort units): a_n | b_n | a_f | b_f | Wab_f | Wo_f
    unsigned short* ws    = (unsigned short*)d_ws;
    unsigned short* a_n   = ws;
    unsigned short* b_n   = ws + 1048576;
    unsigned short* a_f   = ws + 2097152;
    unsigned short* b_f   = ws + 3145728;
    unsigned short* Wab_f = ws + 4194304;
    unsigned short* Wo_f  = ws + 4210688;
    const size_t WS_NEEDED = (size_t)(4210688 + 131072) * 2;
    if (ws_size < WS_NEEDED) return;   // diagnosable: output stays poisoned

    k_wrepack<<<72, 256, 0, stream>>>(Wa, Wb, Wo, Wab_f, Wo_f);
    k_lnproj<<<512, 256, 0, stream>>>(m, lnw, lnb, ba, bb, Wab_f, a_n, b_n);
    k_abrepack<<<1024, 256, 0, stream>>>(a_n, b_n, a_f, b_f);
    k_outer<<<256, 512, 0, stream>>>(a_f, b_f, Wo_f, bo, out);
}